// Round 1
// baseline (108.149 us; speedup 1.0000x reference)
//
#include <hip/hip_runtime.h>

// Problem: B,H,W,D = 64,32,32,64 ; K=1024 ; N = 65536
#define NPTS   65536
#define DDIM   64
#define KCODES 1024
#define QOUT_ELEMS (NPTS * DDIM)

typedef _Float16 half8    __attribute__((ext_vector_type(8)));
typedef float    floatx16 __attribute__((ext_vector_type(16)));
typedef unsigned int uint;

// ws: ehp [0,128K) chunk-major f16 | elp [128K,256K) | e2 packed pairs [256K,260K)
#define WS_EHP   0
#define WS_ELP   (128*1024)
#define WS_E2    (256*1024)

union H8U { half8 v; uint u[4]; };

// ---------------------------------------------------------------------------
// Prep: one wave per code. fp16 hi/lo split, CHUNK-MAJOR tiles:
// tile T=k>>5, chunk j=d>>3, code-in-tile c=k&31:
//   byte off = T*4096 + j*512 + c*16 + (d&7)*2
// Also packs (e2h,e2l) per code.
// ---------------------------------------------------------------------------
__global__ void eprep_kernel(const float* __restrict__ emb, char* __restrict__ ws) {
    const int tid = threadIdx.x;
    const int w = tid >> 6, d = tid & 63;
    const int k = blockIdx.x * 4 + w;
    float v = emb[(size_t)k * DDIM + d];
    _Float16 h = (_Float16)v;
    _Float16 l = (_Float16)(v - (float)h);
    size_t off = (size_t)(k >> 5) * 4096 + (size_t)(d >> 3) * 512
               + (size_t)(k & 31) * 16 + (size_t)(d & 7) * 2;
    *(_Float16*)(ws + WS_EHP + off) = h;
    *(_Float16*)(ws + WS_ELP + off) = l;
    float s = v * v;
    #pragma unroll
    for (int m = 1; m < 64; m <<= 1) s += __shfl_xor(s, m, 64);
    if (d == 0) {
        _Float16 e2h = (_Float16)s;
        _Float16 e2l = (_Float16)(s - (float)e2h);
        unsigned short hb = *(unsigned short*)&e2h;
        unsigned short lb = *(unsigned short*)&e2l;
        ((uint*)(ws + WS_E2))[k] = (uint)hb | ((uint)lb << 16);
    }
}

// ---------------------------------------------------------------------------
// Main: grid 512, block 256 = 4 waves. Wave w owns 32 points (pgrp*128+w*32+col)
// over the FULL K=1024 (32 tiles of 32 codes) -> argmin completes in-wave.
//
// Round-N restructure: NO LDS staging, NO barriers in the main loop.
// ws is 260KB (L1/L2-resident); each wave loads its B fragments directly from
// global (8x dwordx4, contiguous 1KB per wave-load) with a one-tile-ahead
// register double buffer. The 13-MFMA chain is split into two independent
// chains (hh x4 + e2 = 5 deep, hl x4 + lh x4 = 8 deep) combined by 16 VALU
// adds -> dep depth fits under the per-tile MFMA issue window; matrix pipe
// can saturate at 2 waves/SIMD.
//
// MFMA 32x32x16 f16 layouts (verified round 2, absmax 0):
//   A[m][k]: m=lane&31, k=(lane>>5)*8+j ; B same with n=lane&31 ;
//   C/D: col=lane&31, row=(r&3)+8*(r>>2)+4*(lane>>5)
// ---------------------------------------------------------------------------
#define MFMA(A,B,C) __builtin_amdgcn_mfma_f32_32x32x16_f16(A,B,C,0,0,0)

__global__ __launch_bounds__(256, 2) void vq_kernel(
    const float* __restrict__ z,
    const char* __restrict__ ws_c,
    const float* __restrict__ emb,
    float* __restrict__ out)
{
    const int tid  = threadIdx.x;
    const int lane = tid & 63;
    const int w    = __builtin_amdgcn_readfirstlane(tid >> 6);
    const int col  = lane & 31;
    const int sel8 = lane >> 5;
    const int pgrp = blockIdx.x;

    __shared__ int s_final[128];

    // ---- A fragments: a = -2 z[pt], hi/lo fp16 ----
    const int pt = pgrp * 128 + w * 32 + col;
    half8 ah[4], al[4];
    {
        const float* zrow = z + (size_t)pt * DDIM + sel8 * 8;
        #pragma unroll
        for (int ks = 0; ks < 4; ++ks) {
            float4 u0 = *(const float4*)(zrow + ks * 16);
            float4 u1 = *(const float4*)(zrow + ks * 16 + 4);
            float tv[8] = {u0.x, u0.y, u0.z, u0.w, u1.x, u1.y, u1.z, u1.w};
            #pragma unroll
            for (int j = 0; j < 8; ++j) {
                float a = -2.0f * tv[j];
                _Float16 hh = (_Float16)a;
                ah[ks][j] = hh;
                al[ks][j] = (_Float16)(a - (float)hh);
            }
        }
    }
    // e2-step A operand: A[m][k]=1 ONLY for k=0,1 (sel8==0 lanes). sel8==1 lanes
    // MUST be zero or e2 gets double-counted.
    half8 ahE;
    { H8U t0; t0.u[0] = (sel8 == 0) ? 0x3C003C00u : 0u;
      t0.u[1] = t0.u[2] = t0.u[3] = 0u; ahE = t0.v; }

    const floatx16 zeroC = {};   // hoisted zero C-operand

    float best[16];
    int   bt[16];
    #pragma unroll
    for (int r = 0; r < 16; ++r) { best[r] = 3.4e38f; bt[r] = 0; }

    // Per-lane fragment base inside a tile (chunk-major layout).
    const int myoff = sel8 * 512 + col * 16;
    const char* ebase = ws_c + myoff;                  // + t*4096 + ks*1024
    const uint* e2p   = (const uint*)(ws_c + WS_E2);   // packed (e2h,e2l)

    half8 bhA[4], blA[4], bhB[4], blB[4];
    uint  eA, eB;

#define LOADT(T, BH, BL, E2) do {                                        \
    const char* _b = ebase + (size_t)(T) * 4096;                         \
    _Pragma("unroll")                                                    \
    for (int ks = 0; ks < 4; ++ks) {                                     \
        BH[ks] = *(const half8*)(_b + ks * 1024);                        \
        BL[ks] = *(const half8*)(_b + WS_ELP + ks * 1024);               \
    }                                                                    \
    E2 = e2p[(T) * 32 + col];                                            \
} while (0)

#define TILE(T, BH, BL, E2) do {                                         \
    H8U _u; _u.u[0] = (E2); _u.u[1] = _u.u[2] = _u.u[3] = 0u;            \
    __builtin_amdgcn_s_setprio(1);                                       \
    floatx16 _a0 = MFMA(ah[0], BH[0], zeroC);                            \
    _a0 = MFMA(ah[1], BH[1], _a0);                                       \
    _a0 = MFMA(ah[2], BH[2], _a0);                                       \
    _a0 = MFMA(ah[3], BH[3], _a0);                                       \
    _a0 = MFMA(ahE,   _u.v,  _a0);                                       \
    floatx16 _a1 = MFMA(ah[0], BL[0], zeroC);                            \
    _a1 = MFMA(ah[1], BL[1], _a1);                                       \
    _a1 = MFMA(ah[2], BL[2], _a1);                                       \
    _a1 = MFMA(ah[3], BL[3], _a1);                                       \
    _a1 = MFMA(al[0], BH[0], _a1);                                       \
    _a1 = MFMA(al[1], BH[1], _a1);                                       \
    _a1 = MFMA(al[2], BH[2], _a1);                                       \
    _a1 = MFMA(al[3], BH[3], _a1);                                       \
    __builtin_amdgcn_s_setprio(0);                                       \
    _Pragma("unroll")                                                    \
    for (int r = 0; r < 16; ++r) {                                       \
        float _d = _a0[r] + _a1[r];                                      \
        bool  _c = _d < best[r];     /* strict <: earliest tile wins */  \
        best[r] = _c ? _d  : best[r];                                    \
        bt[r]   = _c ? (T) : bt[r];                                      \
    }                                                                    \
} while (0)

    LOADT(0, bhA, blA, eA);
    for (int t = 0; t < 32; t += 2) {
        LOADT(t + 1, bhB, blB, eB);        // prefetch B while computing A
        TILE(t, bhA, blA, eA);
        int tn = (t + 2 < 32) ? (t + 2) : 0;   // clamped: harmless reload at end
        LOADT(tn, bhA, blA, eA);           // prefetch A while computing B
        TILE(t + 1, bhB, blB, eB);
    }

#undef LOADT
#undef TILE

    // materialize codes; butterfly argmin across the 32 columns (within sel8 group)
    int code[16];
    #pragma unroll
    for (int r = 0; r < 16; ++r) code[r] = bt[r] * 32 + col;
    #pragma unroll
    for (int m = 1; m < 32; m <<= 1) {
        #pragma unroll
        for (int r = 0; r < 16; ++r) {
            float ov = __shfl_xor(best[r], m, 64);
            int   oc = __shfl_xor(code[r], m, 64);
            bool c = (ov < best[r]) || (ov == best[r] && oc < code[r]);
            best[r] = c ? ov : best[r];
            code[r] = c ? oc : code[r];
        }
    }
    if (col == 0) {   // lanes 0 and 32: 16 rows each
        #pragma unroll
        for (int r = 0; r < 16; ++r) {
            int row = (r & 3) + 8 * (r >> 2) + 4 * sel8;
            s_final[w * 32 + row] = code[r];
        }
    }
    __syncthreads();

    // indices (coalesced) + quantized gather: 128 pts x 16 float4
    if (tid < 128)
        out[QOUT_ELEMS + (size_t)pgrp * 128 + tid] = (float)s_final[tid];
    float4* outq = (float4*)out;
    const float4* emb4 = (const float4*)emb;
    #pragma unroll
    for (int it = 0; it < 8; ++it) {
        int f  = it * 256 + tid;
        int p  = f >> 4;
        int d4 = f & 15;
        int ks = s_final[p];
        outq[((size_t)pgrp * 128 + p) * (DDIM / 4) + d4] =
            emb4[(size_t)ks * (DDIM / 4) + d4];
    }
}

extern "C" void kernel_launch(void* const* d_in, const int* in_sizes, int n_in,
                              void* d_out, int out_size, void* d_ws, size_t ws_size,
                              hipStream_t stream) {
    const float* z   = (const float*)d_in[0];
    const float* emb = (const float*)d_in[1];
    float* out = (float*)d_out;
    char* ws = (char*)d_ws;

    eprep_kernel<<<KCODES / 4, 256, 0, stream>>>(emb, ws);
    vq_kernel<<<NPTS / 128, 256, 0, stream>>>(z, ws, emb, out);
}